// Round 14
// baseline (1033.745 us; speedup 1.0000x reference)
//
#include <hip/hip_runtime.h>
#include <hip/hip_bf16.h>

using bf16 = __hip_bfloat16;
typedef __attribute__((ext_vector_type(4))) float  f32x4;
typedef __attribute__((ext_vector_type(8))) short  s16x8;

#define QSTRIDE 1040   // 128*8 + 16 pad (bf16 elems per k-quad block)
#define ASTRIDE 520    // 64*8 + 8 pad   (gemm_ln A tile)
#define BSTRIDE 2064   // 256*8 + 16 pad (gemm_ln B tile)
#define CMAX 256
#define RMAX 128

// ---------------------------------------------------------------------------
// fp32 -> bf16 weight conversion (14 segments, pre-concatenated arenas).
// ---------------------------------------------------------------------------
struct ConvDesc { const float* src[14]; int dstoff[14]; int cnt[14]; };

__global__ __launch_bounds__(256)
void conv_weights(ConvDesc d, bf16* __restrict__ dst)
{
    const int seg = blockIdx.x >> 6;
    const int blk = blockIdx.x & 63;
    const float* __restrict__ s = d.src[seg];
    bf16* __restrict__ o = dst + d.dstoff[seg];
    const int n = d.cnt[seg];
    for (int i = blk * 256 + threadIdx.x; i < n; i += 64 * 256)
        o[i] = __float2bfloat16(s[i]);
}

// ---------------------------------------------------------------------------
// Phase 1: wave-per-row streaming scan of H [8192,2048] fp32 (exactly 0/1).
// NO atomics, NO barriers, NO LDS. Produces: row lists (ballot-prefix
// positions, register-accumulated base) + 64-bit nonzero bitmap per
// (row, word) into bmp[row*32 + w]  (w = g*4+sub; bit l = col g*256+l*4+sub).
// Row-list column order is permuted (softmax order-invariant).
// ---------------------------------------------------------------------------
__global__ __launch_bounds__(256)
void build_rows(const float* __restrict__ H, unsigned long long* __restrict__ bmp,
                int* __restrict__ row_cnt, unsigned short* __restrict__ row_idx)
{
    const int wv   = threadIdx.x >> 6;
    const int lane = threadIdx.x & 63;
    const int n    = blockIdx.x * 4 + wv;
    const float* __restrict__ Hp = H + (size_t)n * 2048;
    unsigned short* __restrict__ rl = row_idx + (size_t)n * RMAX;

    const unsigned long long below = (1ull << lane) - 1;

    f32x4 v[8];
#pragma unroll
    for (int g = 0; g < 8; g++)
        v[g] = *(const f32x4*)(Hp + g * 256 + lane * 4);

    unsigned long long mw = 0;
    int base = 0;
#pragma unroll
    for (int g = 0; g < 8; g++) {
#pragma unroll
        for (int sub = 0; sub < 4; sub++) {
            const bool nz = (v[g][sub] != 0.f);
            const unsigned long long mask = __ballot(nz);
            if (nz) {
                const int pos = base + __popcll(mask & below);
                if (pos < RMAX)
                    rl[pos] = (unsigned short)(g * 256 + lane * 4 + sub);
            }
            base += __popcll(mask);
            if (lane == g * 4 + sub) mw = mask;
        }
    }
    if (lane < 32) bmp[(size_t)n * 32 + lane] = mw;
    if (lane == 0) row_cnt[n] = (base < RMAX) ? base : RMAX;
}

// ---------------------------------------------------------------------------
// Phase 2: col lists from the 2 MB bitmap (L2-resident). 32 single-wave
// blocks; wave = one word index widx. Lane l owns column
// c = (widx>>2)*256 + l*4 + (widx&3); scans 8192 rows with a deterministic
// register counter. NO atomics.
// ---------------------------------------------------------------------------
__global__ __launch_bounds__(64)
void build_cols(const unsigned long long* __restrict__ bmp,
                int* __restrict__ col_cnt, unsigned short* __restrict__ col_idx)
{
    const int widx = blockIdx.x;            // 0..31
    const int lane = threadIdx.x;           // 0..63
    const int c    = (widx >> 2) * 256 + lane * 4 + (widx & 3);
    unsigned short* __restrict__ cl = col_idx + (size_t)c * CMAX;

    int cnt = 0;
    for (int r0 = 0; r0 < 8192; r0 += 8) {
        unsigned long long w[8];
#pragma unroll
        for (int k = 0; k < 8; k++)
            w[k] = bmp[(size_t)(r0 + k) * 32 + widx];
#pragma unroll
        for (int k = 0; k < 8; k++) {
            if ((w[k] >> lane) & 1ull) {
                if (cnt < CMAX) cl[cnt] = (unsigned short)(r0 + k);
                cnt++;
            }
        }
    }
    col_cnt[c] = (cnt < CMAX) ? cnt : CMAX;
}

// ---------------------------------------------------------------------------
// Fused node+edge projection: rows 0..8191 = x_0@node_w^T+node_b,
// rows 8192..10239 = x_1@edge_w^T+edge_b. A fp32 converted in staging.
// Grid: 80 row-tiles x 2 col-tiles = 160 blocks.
// ---------------------------------------------------------------------------
__global__ __launch_bounds__(256, 2)
void gemm_proj(const float* __restrict__ X0, const float* __restrict__ X1,
               const bf16* __restrict__ Wc, const bf16* __restrict__ biasc,
               bf16* __restrict__ outB)
{
    __shared__ __align__(16) bf16 As[4 * QSTRIDE];
    __shared__ __align__(16) bf16 Bs[4 * QSTRIDE];

    const int t    = threadIdx.x;
    const int lane = t & 63;
    const int w    = t >> 6;
    const int wm   = (w >> 1) * 64;
    const int wn   = (w & 1) * 64;
    const int bt   = blockIdx.x >> 1;
    const int tn   = (blockIdx.x & 1) * 128;
    if (bt >= 80) return;

    const float* __restrict__ A = (bt < 64) ? X0 : X1;
    const int arow = (bt < 64) ? bt * 128 : (bt - 64) * 128;
    const bf16* __restrict__ W    = Wc    + ((bt < 64) ? 0 : 65536);
    const bf16* __restrict__ bias = biasc + ((bt < 64) ? 0 : 256);
    const int tm = bt * 128;

    f32x4 acc[4][4];
#pragma unroll
    for (int i = 0; i < 4; i++)
#pragma unroll
        for (int j = 0; j < 4; j++)
#pragma unroll
            for (int r = 0; r < 4; r++) acc[i][j][r] = 0.f;

    const int m0 = t >> 2,         q0 = t & 3;
    const int m1 = (t + 256) >> 2, q1 = (t + 256) & 3;
    const int fq = lane >> 4, fr = lane & 15;

    for (int k0 = 0; k0 < 256; k0 += 32) {
        f32x4 a0l = *(const f32x4*)(A + (size_t)(arow + m0) * 256 + k0 + q0 * 8);
        f32x4 a0h = *(const f32x4*)(A + (size_t)(arow + m0) * 256 + k0 + q0 * 8 + 4);
        f32x4 a1l = *(const f32x4*)(A + (size_t)(arow + m1) * 256 + k0 + q1 * 8);
        f32x4 a1h = *(const f32x4*)(A + (size_t)(arow + m1) * 256 + k0 + q1 * 8 + 4);
        union { s16x8 v; bf16 e[8]; } u0, u1;
#pragma unroll
        for (int j = 0; j < 4; j++) {
            u0.e[j] = __float2bfloat16(a0l[j]); u0.e[4 + j] = __float2bfloat16(a0h[j]);
            u1.e[j] = __float2bfloat16(a1l[j]); u1.e[4 + j] = __float2bfloat16(a1h[j]);
        }
        s16x8 sb0 = *(const s16x8*)(W + (size_t)(tn + m0) * 256 + k0 + q0 * 8);
        s16x8 sb1 = *(const s16x8*)(W + (size_t)(tn + m1) * 256 + k0 + q1 * 8);

        __syncthreads();
        *(s16x8*)&As[q0 * QSTRIDE + m0 * 8] = u0.v;
        *(s16x8*)&As[q1 * QSTRIDE + m1 * 8] = u1.v;
        *(s16x8*)&Bs[q0 * QSTRIDE + m0 * 8] = sb0;
        *(s16x8*)&Bs[q1 * QSTRIDE + m1 * 8] = sb1;
        __syncthreads();

        s16x8 af[4], bfv[4];
#pragma unroll
        for (int i = 0; i < 4; i++) {
            af[i]  = *(const s16x8*)&As[fq * QSTRIDE + (wm + i * 16 + fr) * 8];
            bfv[i] = *(const s16x8*)&Bs[fq * QSTRIDE + (wn + i * 16 + fr) * 8];
        }
#pragma unroll
        for (int i = 0; i < 4; i++)
#pragma unroll
            for (int j = 0; j < 4; j++)
                acc[i][j] = __builtin_amdgcn_mfma_f32_16x16x32_bf16(
                    af[i], bfv[j], acc[i][j], 0, 0, 0);
    }

#pragma unroll
    for (int j = 0; j < 4; j++) {
        const int ncol = tn + wn + j * 16 + fr;
        const float bj = __bfloat162float(bias[ncol]);
#pragma unroll
        for (int i = 0; i < 4; i++)
#pragma unroll
            for (int r = 0; r < 4; r++) {
                const int mrow = tm + wm + i * 16 + fq * 4 + r;
                outB[(size_t)mrow * 256 + ncol] = __float2bfloat16(acc[i][j][r] + bj);
            }
    }
}

// ---------------------------------------------------------------------------
// Dual MFMA GEMM (two independent problems, block-range split), bf16 in/out.
// ---------------------------------------------------------------------------
__global__ __launch_bounds__(256, 2)
void gemm_dual(const bf16* __restrict__ A0, const bf16* __restrict__ W0,
               const bf16* __restrict__ bias0, bf16* __restrict__ out0,
               int N0, int tiles0, int nblk0,
               const bf16* __restrict__ A1, const bf16* __restrict__ W1,
               const bf16* __restrict__ bias1, bf16* __restrict__ out1,
               int N1, int tiles1)
{
    __shared__ __align__(16) bf16 As[4 * QSTRIDE];
    __shared__ __align__(16) bf16 Bs[4 * QSTRIDE];

    const int t    = threadIdx.x;
    const int lane = t & 63;
    const int w    = t >> 6;
    const int wm   = (w >> 1) * 64;
    const int wn   = (w & 1) * 64;

    const bool second = (blockIdx.x >= (unsigned)nblk0);
    const int  bi     = second ? (blockIdx.x - nblk0) : blockIdx.x;
    const bf16* __restrict__ A    = second ? A1 : A0;
    const bf16* __restrict__ W    = second ? W1 : W0;
    const bf16* __restrict__ bias = second ? bias1 : bias0;
    bf16* __restrict__ outB       = second ? out1 : out0;
    const int N      = second ? N1 : N0;
    const int tilesN = second ? tiles1 : tiles0;
    const int tm = (bi / tilesN) * 128;
    const int tn = (bi % tilesN) * 128;

    f32x4 acc[4][4];
#pragma unroll
    for (int i = 0; i < 4; i++)
#pragma unroll
        for (int j = 0; j < 4; j++)
#pragma unroll
            for (int r = 0; r < 4; r++) acc[i][j][r] = 0.f;

    const int m0 = t >> 2,         q0 = t & 3;
    const int m1 = (t + 256) >> 2, q1 = (t + 256) & 3;
    const int fq = lane >> 4, fr = lane & 15;

    for (int k0 = 0; k0 < 256; k0 += 32) {
        s16x8 sa0 = *(const s16x8*)(A + (size_t)(tm + m0) * 256 + k0 + q0 * 8);
        s16x8 sa1 = *(const s16x8*)(A + (size_t)(tm + m1) * 256 + k0 + q1 * 8);
        s16x8 sb0 = *(const s16x8*)(W + (size_t)(tn + m0) * 256 + k0 + q0 * 8);
        s16x8 sb1 = *(const s16x8*)(W + (size_t)(tn + m1) * 256 + k0 + q1 * 8);

        __syncthreads();
        *(s16x8*)&As[q0 * QSTRIDE + m0 * 8] = sa0;
        *(s16x8*)&As[q1 * QSTRIDE + m1 * 8] = sa1;
        *(s16x8*)&Bs[q0 * QSTRIDE + m0 * 8] = sb0;
        *(s16x8*)&Bs[q1 * QSTRIDE + m1 * 8] = sb1;
        __syncthreads();

        s16x8 af[4], bfv[4];
#pragma unroll
        for (int i = 0; i < 4; i++) {
            af[i]  = *(const s16x8*)&As[fq * QSTRIDE + (wm + i * 16 + fr) * 8];
            bfv[i] = *(const s16x8*)&Bs[fq * QSTRIDE + (wn + i * 16 + fr) * 8];
        }
#pragma unroll
        for (int i = 0; i < 4; i++)
#pragma unroll
            for (int j = 0; j < 4; j++)
                acc[i][j] = __builtin_amdgcn_mfma_f32_16x16x32_bf16(
                    af[i], bfv[j], acc[i][j], 0, 0, 0);
    }

#pragma unroll
    for (int j = 0; j < 4; j++) {
        const int ncol = tn + wn + j * 16 + fr;
        const float bj = __bfloat162float(bias[ncol]);
#pragma unroll
        for (int i = 0; i < 4; i++)
#pragma unroll
            for (int r = 0; r < 4; r++) {
                const int mrow = tm + wm + i * 16 + fq * 4 + r;
                outB[(size_t)mrow * N + ncol] = __float2bfloat16(acc[i][j][r] + bj);
            }
    }
}

// ---------------------------------------------------------------------------
// Fused out-proj + residual + LayerNorm. Block = 64 rows x 256 cols.
// y = LN(xp + A@W^T + bias) * g + b -> fp32 d_out (+ optional bf16 copy).
// ---------------------------------------------------------------------------
__global__ __launch_bounds__(256, 2)
void gemm_ln(const bf16* __restrict__ A, const bf16* __restrict__ W,
             const float* __restrict__ biasF, const bf16* __restrict__ xp,
             const float* __restrict__ g, const float* __restrict__ b,
             float* __restrict__ outF, bf16* __restrict__ outB)
{
    __shared__ __align__(16) bf16 As[4 * ASTRIDE];
    __shared__ __align__(16) bf16 Bs[4 * BSTRIDE];
    __shared__ float rs1[64], rs2[64];

    const int t    = threadIdx.x;
    const int lane = t & 63;
    const int w    = t >> 6;
    const int fq   = lane >> 4;
    const int fr   = lane & 15;
    const int tm   = blockIdx.x * 64;

    if (t < 64) { rs1[t] = 0.f; rs2[t] = 0.f; }

    f32x4 acc[4][4];
#pragma unroll
    for (int i = 0; i < 4; i++)
#pragma unroll
        for (int j = 0; j < 4; j++)
#pragma unroll
            for (int r = 0; r < 4; r++) acc[i][j][r] = 0.f;

    const int mA = t >> 2, qA = t & 3;

    for (int k0 = 0; k0 < 256; k0 += 32) {
        s16x8 sa = *(const s16x8*)(A + (size_t)(tm + mA) * 256 + k0 + qA * 8);
        s16x8 sb[4];
#pragma unroll
        for (int s = 0; s < 4; s++)
            sb[s] = *(const s16x8*)(W + (size_t)(mA + 64 * s) * 256 + k0 + qA * 8);

        __syncthreads();
        *(s16x8*)&As[qA * ASTRIDE + mA * 8] = sa;
#pragma unroll
        for (int s = 0; s < 4; s++)
            *(s16x8*)&Bs[qA * BSTRIDE + (mA + 64 * s) * 8] = sb[s];
        __syncthreads();

        s16x8 af[4], bfv[4];
#pragma unroll
        for (int i = 0; i < 4; i++) {
            af[i]  = *(const s16x8*)&As[fq * ASTRIDE + (i * 16 + fr) * 8];
            bfv[i] = *(const s16x8*)&Bs[fq * BSTRIDE + (w * 64 + i * 16 + fr) * 8];
        }
#pragma unroll
        for (int i = 0; i < 4; i++)
#pragma unroll
            for (int j = 0; j < 4; j++)
                acc[i][j] = __builtin_amdgcn_mfma_f32_16x16x32_bf16(
                    af[i], bfv[j], acc[i][j], 0, 0, 0);
    }

    float bj[4], gj[4], bbj[4];
    int colv[4];
#pragma unroll
    for (int j = 0; j < 4; j++) {
        colv[j] = w * 64 + j * 16 + fr;
        bj[j]  = biasF[colv[j]];
        gj[j]  = g[colv[j]];
        bbj[j] = b[colv[j]];
    }

#pragma unroll
    for (int i = 0; i < 4; i++) {
#pragma unroll
        for (int r = 0; r < 4; r++) {
            const int row = i * 16 + fq * 4 + r;
            float t1 = 0.f, t2 = 0.f;
#pragma unroll
            for (int j = 0; j < 4; j++) {
                float v = acc[i][j][r] + bj[j]
                        + __bfloat162float(xp[(size_t)(tm + row) * 256 + colv[j]]);
                acc[i][j][r] = v;
                t1 += v;
                t2 += v * v;
            }
#pragma unroll
            for (int o = 1; o < 16; o <<= 1) {
                t1 += __shfl_xor(t1, o);
                t2 += __shfl_xor(t2, o);
            }
            if (fr == 0) {
                atomicAdd(&rs1[row], t1);
                atomicAdd(&rs2[row], t2);
            }
        }
    }
    __syncthreads();

#pragma unroll
    for (int i = 0; i < 4; i++) {
#pragma unroll
        for (int r = 0; r < 4; r++) {
            const int row = i * 16 + fq * 4 + r;
            const float mu  = rs1[row] * (1.f / 256.f);
            const float var = rs2[row] * (1.f / 256.f) - mu * mu;
            const float rstd = rsqrtf(var + 1e-5f);
#pragma unroll
            for (int j = 0; j < 4; j++) {
                const float y = (acc[i][j][r] - mu) * rstd * gj[j] + bbj[j];
                outF[(size_t)(tm + row) * 256 + colv[j]] = y;
                if (outB) outB[(size_t)(tm + row) * 256 + colv[j]] = __float2bfloat16(y);
            }
        }
    }
}

// ---------------------------------------------------------------------------
// Sparse masked attention, vectorized gather. Block = query row, wave = head.
// 8 groups x 8 lanes: group = neighbor, lane = 8-dim slice (16 B loads).
// ---------------------------------------------------------------------------
__global__ __launch_bounds__(256)
void sparse_attn(const bf16* __restrict__ Q, int qs,
                 const bf16* __restrict__ Kb, const bf16* __restrict__ Vb, int kvs,
                 const int* __restrict__ cnts, const unsigned short* __restrict__ idx,
                 int lmax, int idxmask, bf16* __restrict__ out)
{
    __shared__ float sc[4][CMAX];
    __shared__ unsigned short nls[CMAX];
    const int qi   = blockIdx.x;
    const int h    = threadIdx.x >> 6;
    const int lane = threadIdx.x & 63;
    const int grp  = lane >> 3;
    const int sub  = lane & 7;

    int n = cnts[qi];
    if (n > lmax) n = lmax;

    if (h == 0)
        for (int i = lane; i < n; i += 64)
            nls[i] = (unsigned short)(((int)idx[(size_t)qi * lmax + i]) & idxmask);
    __syncthreads();

    if (n <= 0) {
        out[(size_t)qi * 256 + h * 64 + lane] = __float2bfloat16(0.f);
        return;
    }

    float qv[8];
    {
        union { f32x4 v; unsigned short u[8]; } qu;
        qu.v = *(const f32x4*)(Q + (size_t)qi * qs + h * 64 + sub * 8);
#pragma unroll
        for (int j = 0; j < 8; j++)
            qv[j] = __uint_as_float(((unsigned)qu.u[j]) << 16) * 0.125f;
    }

    float mx = -1e30f;
#pragma unroll 2
    for (int base = 0; base < n; base += 8) {
        const int i = base + grp;
        float s = -1e30f;
        if (i < n) {
            const int nb = nls[i];
            union { f32x4 v; unsigned short u[8]; } ku;
            ku.v = *(const f32x4*)(Kb + (size_t)nb * kvs + h * 64 + sub * 8);
            float a = 0.f;
#pragma unroll
            for (int j = 0; j < 8; j++)
                a += __uint_as_float(((unsigned)ku.u[j]) << 16) * qv[j];
            a += __shfl_xor(a, 1);
            a += __shfl_xor(a, 2);
            a += __shfl_xor(a, 4);
            if (sub == 0) sc[h][i] = a;
            s = a;
        }
        mx = fmaxf(mx, s);
    }
#pragma unroll
    for (int o = 32; o > 0; o >>= 1) mx = fmaxf(mx, __shfl_xor(mx, o));

    float sum = 0.f;
    for (int base = 0; base < n; base += 64) {
        const int i = base + lane;
        if (i < n) {
            const float p = __expf(sc[h][i] - mx);
            sc[h][i] = p;
            sum += p;
        }
    }
#pragma unroll
    for (int o = 32; o > 0; o >>= 1) sum += __shfl_xor(sum, o);
    const float inv = 1.f / sum;

    float oa[8];
#pragma unroll
    for (int j = 0; j < 8; j++) oa[j] = 0.f;
#pragma unroll 2
    for (int base = 0; base < n; base += 8) {
        const int i = base + grp;
        if (i < n) {
            const float p = sc[h][i];
            const int nb = nls[i];
            union { f32x4 v; unsigned short u[8]; } vu;
            vu.v = *(const f32x4*)(Vb + (size_t)nb * kvs + h * 64 + sub * 8);
#pragma unroll
            for (int j = 0; j < 8; j++)
                oa[j] += p * __uint_as_float(((unsigned)vu.u[j]) << 16);
        }
    }
#pragma unroll
    for (int j = 0; j < 8; j++) {
        oa[j] += __shfl_xor(oa[j], 8);
        oa[j] += __shfl_xor(oa[j], 16);
        oa[j] += __shfl_xor(oa[j], 32);
    }
    if (grp == 0) {
        union { s16x8 v; bf16 e[8]; } ou;
#pragma unroll
        for (int j = 0; j < 8; j++) ou.e[j] = __float2bfloat16(oa[j] * inv);
        *(s16x8*)(out + (size_t)qi * 256 + h * 64 + sub * 8) = ou.v;
    }
}

// ---------------------------------------------------------------------------
extern "C" void kernel_launch(void* const* d_in, const int* in_sizes, int n_in,
                              void* d_out, int out_size, void* d_ws, size_t ws_size,
                              hipStream_t stream)
{
    const int N = 8192, E = 2048;

    float* out0 = (float*)d_out;                   // x_0_u [N,256] fp32
    float* out1 = (float*)d_out + (size_t)N * 256; // x_1_u [E,256] fp32

    char* wp = (char*)d_ws;
    auto carve = [&](size_t bytes) { void* p = wp; wp += (bytes + 15) & ~size_t(15); return p; };

    bf16*  wcat    = (bf16*)          carve(657408 * 2);
    int*   col_cnt = (int*)           carve((size_t)E * 4);
    int*   row_cnt = (int*)           carve((size_t)N * 4);
    unsigned short* col_idx = (unsigned short*)carve((size_t)E * CMAX * 2);
    unsigned short* row_idx = (unsigned short*)carve((size_t)N * RMAX * 2);
    unsigned long long* bmp = (unsigned long long*)carve((size_t)N * 32 * 8); // 2 MB
    bf16*  xp01    = (bf16*) carve((size_t)(N + E) * 256 * 2);  // x0p | x1p
    bf16*  kvq     = (bf16*) carve((size_t)N * 768 * 2);        // k1|v1|q2
    bf16*  q1      = (bf16*) carve((size_t)E * 256 * 2);
    bf16*  attn1   = (bf16*) carve((size_t)E * 256 * 2);
    bf16*  x1u_b   = (bf16*) carve((size_t)E * 256 * 2);
    bf16*  kv2     = (bf16*) carve((size_t)E * 512 * 2);
    bf16*  attn2   = (bf16*) carve((size_t)N * 256 * 2);

    bf16* x0p = xp01;
    bf16* x1p = xp01 + (size_t)N * 256;

    // wcat element offsets (all 8-elem aligned)
    const int O_PW   = 0;        // node_w | edge_w           (131072)
    const int O_PB   = 131072;   // node_b | edge_b           (512)
    const int O_KVQ  = 131584;   // n2e Wk,Wv | e2n Wq        (196608)
    const int O_KVQB = 328192;   // n2e bk,bv | e2n bq        (768)
    const int O_Q1W  = 328960;   // n2e Wq                    (65536)
    const int O_Q1B  = 394496;   // n2e bq                    (256)
    const int O_KV2W = 394752;   // e2n Wk,Wv                 (131072)
    const int O_KV2B = 525824;   // e2n bk,bv                 (512)
    const int O_O1W  = 526336;   // n2e_out_w                 (65536)
    const int O_O2W  = 591872;   // e2n_out_w                 (65536)

    ConvDesc cd;
    const float* srcs[14] = {
        (const float*)d_in[3], (const float*)d_in[5],
        (const float*)d_in[4], (const float*)d_in[6],
        (const float*)d_in[7] + 65536, (const float*)d_in[11],
        (const float*)d_in[8] + 256,   (const float*)d_in[12],
        (const float*)d_in[7],         (const float*)d_in[8],
        (const float*)d_in[11] + 65536,(const float*)d_in[12] + 256,
        (const float*)d_in[9],         (const float*)d_in[13]
    };
    const int offs[14] = {O_PW, O_PW + 65536, O_PB, O_PB + 256,
                          O_KVQ, O_KVQ + 131072, O_KVQB, O_KVQB + 512,
                          O_Q1W, O_Q1B, O_KV2W, O_KV2B, O_O1W, O_O2W};
    const int cnts[14] = {65536, 65536, 256, 256, 131072, 65536, 512, 256,
                          65536, 256, 131072, 512, 65536, 65536};
    for (int i = 0; i < 14; i++) { cd.src[i] = srcs[i]; cd.dstoff[i] = offs[i]; cd.cnt[i] = cnts[i]; }

    // 1. weights -> bf16 arena
    conv_weights<<<14 * 64, 256, 0, stream>>>(cd, wcat);

    // 2a. streaming row scan: row lists + bitmap (no atomics/barriers)
    build_rows<<<2048, 256, 0, stream>>>((const float*)d_in[2], bmp, row_cnt, row_idx);
    // 2b. col lists from L2-resident bitmap (no atomics)
    build_cols<<<32, 64, 0, stream>>>(bmp, col_cnt, col_idx);

    // 3. projections
    gemm_proj<<<160, 256, 0, stream>>>((const float*)d_in[0], (const float*)d_in[1],
                                       wcat + O_PW, wcat + O_PB, xp01);

    // 4. fused kvq (384 blocks) + q1 (32 blocks)
    gemm_dual<<<384 + 32, 256, 0, stream>>>(x0p, wcat + O_KVQ, wcat + O_KVQB, kvq,
                                            768, 6, 384,
                                            x1p, wcat + O_Q1W, wcat + O_Q1B, q1,
                                            256, 2);

    // ---- stage 1: node -> edge ----
    sparse_attn<<<E, 256, 0, stream>>>(q1, 256, kvq, kvq + 256, 768,
                                       col_cnt, col_idx, CMAX, N - 1, attn1);
    gemm_ln<<<E / 64, 256, 0, stream>>>(attn1, wcat + O_O1W, (const float*)d_in[10],
                                        x1p, (const float*)d_in[15], (const float*)d_in[16],
                                        out1, x1u_b);

    // ---- stage 2: edge -> node ----
    gemm_dual<<<64, 256, 0, stream>>>(x1u_b, wcat + O_KV2W, wcat + O_KV2B, kv2,
                                      512, 4, 64,
                                      nullptr, nullptr, nullptr, nullptr, 256, 2);
    sparse_attn<<<N, 256, 0, stream>>>(kvq + 512, 768, kv2, kv2 + 256, 512,
                                       row_cnt, row_idx, RMAX, E - 1, attn2);
    gemm_ln<<<N / 64, 256, 0, stream>>>(attn2, wcat + O_O2W, (const float*)d_in[14],
                                        x0p, (const float*)d_in[17], (const float*)d_in[18],
                                        out0, nullptr);
}

// Round 15
// 271.791 us; speedup vs baseline: 3.8035x; 3.8035x over previous
//
#include <hip/hip_runtime.h>
#include <hip/hip_bf16.h>

using bf16 = __hip_bfloat16;
typedef __attribute__((ext_vector_type(4))) float  f32x4;
typedef __attribute__((ext_vector_type(8))) short  s16x8;

#define QSTRIDE 1040   // 128*8 + 16 pad (bf16 elems per k-quad block)
#define ASTRIDE 520    // 64*8 + 8 pad   (gemm_ln A tile)
#define BSTRIDE 2064   // 256*8 + 16 pad (gemm_ln B tile)
#define CMAX 256
#define RMAX 128

// ---------------------------------------------------------------------------
// fp32 -> bf16 weight conversion (14 segments) + col_cnt zero-fill (seg 14).
// ---------------------------------------------------------------------------
struct ConvDesc { const float* src[14]; int dstoff[14]; int cnt[14]; };

__global__ __launch_bounds__(256)
void conv_weights(ConvDesc d, bf16* __restrict__ dst, int* __restrict__ cz, int czn)
{
    const int seg = blockIdx.x >> 6;
    const int blk = blockIdx.x & 63;
    if (seg == 14) {                       // zero col_cnt
        for (int i = blk * 256 + threadIdx.x; i < czn; i += 64 * 256)
            cz[i] = 0;
        return;
    }
    const float* __restrict__ s = d.src[seg];
    bf16* __restrict__ o = dst + d.dstoff[seg];
    const int n = d.cnt[seg];
    for (int i = blk * 256 + threadIdx.x; i < n; i += 64 * 256)
        o[i] = __float2bfloat16(s[i]);
}

// ---------------------------------------------------------------------------
// Sparse neighbor lists from H [8192,2048] fp32 (exactly 0/1).
// KNOWN-BEST (r11, 41 us): 1024 blocks x 8 rows, 2-deep register prefetch.
// r12 (wave-per-row) 82us, r13 (aggregated atomics) 70us, r14 (two-phase
// bitmap) 788us all lost — do not revisit without new counter evidence.
// ---------------------------------------------------------------------------
__global__ __launch_bounds__(256)
void build_lists(const float* __restrict__ H, int* __restrict__ col_cnt,
                 unsigned short* __restrict__ col_idx, int* __restrict__ row_cnt,
                 unsigned short* __restrict__ row_idx)
{
    __shared__ int rc;
    const int t = threadIdx.x;

    int n = blockIdx.x;
    const float* Hp = H + (size_t)n * 2048 + t * 8;
    f32x4 c0 = *(const f32x4*)Hp;
    f32x4 c1 = *(const f32x4*)(Hp + 4);

    while (n < 8192) {
        const int nn = n + 1024;
        f32x4 p0, p1;
        if (nn < 8192) {                       // prefetch next row
            const float* Hq = H + (size_t)nn * 2048 + t * 8;
            p0 = *(const f32x4*)Hq;
            p1 = *(const f32x4*)(Hq + 4);
        }

        if (t == 0) rc = 0;
        __syncthreads();

        float hv[8];
#pragma unroll
        for (int j = 0; j < 4; j++) { hv[j] = c0[j]; hv[4 + j] = c1[j]; }

#pragma unroll
        for (int j = 0; j < 8; j++) {
            if (hv[j] != 0.f) {
                const int e = t * 8 + j;
                const int sr = atomicAdd(&rc, 1);
                if (sr < RMAX) row_idx[(size_t)n * RMAX + sr] = (unsigned short)e;
                const int sc = atomicAdd(&col_cnt[e], 1);
                if (sc < CMAX) col_idx[(size_t)e * CMAX + sc] = (unsigned short)n;
            }
        }
        __syncthreads();
        if (t == 0) row_cnt[n] = (rc < RMAX) ? rc : RMAX;

        n = nn; c0 = p0; c1 = p1;
    }
}

// ---------------------------------------------------------------------------
// Fused node+edge projection: rows 0..8191 = x_0@node_w^T+node_b,
// rows 8192..10239 = x_1@edge_w^T+edge_b. A fp32 converted in staging.
// Grid: 80 row-tiles x 2 col-tiles = 160 blocks.
// ---------------------------------------------------------------------------
__global__ __launch_bounds__(256, 2)
void gemm_proj(const float* __restrict__ X0, const float* __restrict__ X1,
               const bf16* __restrict__ Wc, const bf16* __restrict__ biasc,
               bf16* __restrict__ outB)
{
    __shared__ __align__(16) bf16 As[4 * QSTRIDE];
    __shared__ __align__(16) bf16 Bs[4 * QSTRIDE];

    const int t    = threadIdx.x;
    const int lane = t & 63;
    const int w    = t >> 6;
    const int wm   = (w >> 1) * 64;
    const int wn   = (w & 1) * 64;
    const int bt   = blockIdx.x >> 1;
    const int tn   = (blockIdx.x & 1) * 128;
    if (bt >= 80) return;

    const float* __restrict__ A = (bt < 64) ? X0 : X1;
    const int arow = (bt < 64) ? bt * 128 : (bt - 64) * 128;
    const bf16* __restrict__ W    = Wc    + ((bt < 64) ? 0 : 65536);
    const bf16* __restrict__ bias = biasc + ((bt < 64) ? 0 : 256);
    const int tm = bt * 128;

    f32x4 acc[4][4];
#pragma unroll
    for (int i = 0; i < 4; i++)
#pragma unroll
        for (int j = 0; j < 4; j++)
#pragma unroll
            for (int r = 0; r < 4; r++) acc[i][j][r] = 0.f;

    const int m0 = t >> 2,         q0 = t & 3;
    const int m1 = (t + 256) >> 2, q1 = (t + 256) & 3;
    const int fq = lane >> 4, fr = lane & 15;

    for (int k0 = 0; k0 < 256; k0 += 32) {
        f32x4 a0l = *(const f32x4*)(A + (size_t)(arow + m0) * 256 + k0 + q0 * 8);
        f32x4 a0h = *(const f32x4*)(A + (size_t)(arow + m0) * 256 + k0 + q0 * 8 + 4);
        f32x4 a1l = *(const f32x4*)(A + (size_t)(arow + m1) * 256 + k0 + q1 * 8);
        f32x4 a1h = *(const f32x4*)(A + (size_t)(arow + m1) * 256 + k0 + q1 * 8 + 4);
        union { s16x8 v; bf16 e[8]; } u0, u1;
#pragma unroll
        for (int j = 0; j < 4; j++) {
            u0.e[j] = __float2bfloat16(a0l[j]); u0.e[4 + j] = __float2bfloat16(a0h[j]);
            u1.e[j] = __float2bfloat16(a1l[j]); u1.e[4 + j] = __float2bfloat16(a1h[j]);
        }
        s16x8 sb0 = *(const s16x8*)(W + (size_t)(tn + m0) * 256 + k0 + q0 * 8);
        s16x8 sb1 = *(const s16x8*)(W + (size_t)(tn + m1) * 256 + k0 + q1 * 8);

        __syncthreads();
        *(s16x8*)&As[q0 * QSTRIDE + m0 * 8] = u0.v;
        *(s16x8*)&As[q1 * QSTRIDE + m1 * 8] = u1.v;
        *(s16x8*)&Bs[q0 * QSTRIDE + m0 * 8] = sb0;
        *(s16x8*)&Bs[q1 * QSTRIDE + m1 * 8] = sb1;
        __syncthreads();

        s16x8 af[4], bfv[4];
#pragma unroll
        for (int i = 0; i < 4; i++) {
            af[i]  = *(const s16x8*)&As[fq * QSTRIDE + (wm + i * 16 + fr) * 8];
            bfv[i] = *(const s16x8*)&Bs[fq * QSTRIDE + (wn + i * 16 + fr) * 8];
        }
#pragma unroll
        for (int i = 0; i < 4; i++)
#pragma unroll
            for (int j = 0; j < 4; j++)
                acc[i][j] = __builtin_amdgcn_mfma_f32_16x16x32_bf16(
                    af[i], bfv[j], acc[i][j], 0, 0, 0);
    }

#pragma unroll
    for (int j = 0; j < 4; j++) {
        const int ncol = tn + wn + j * 16 + fr;
        const float bj = __bfloat162float(bias[ncol]);
#pragma unroll
        for (int i = 0; i < 4; i++)
#pragma unroll
            for (int r = 0; r < 4; r++) {
                const int mrow = tm + wm + i * 16 + fq * 4 + r;
                outB[(size_t)mrow * 256 + ncol] = __float2bfloat16(acc[i][j][r] + bj);
            }
    }
}

// ---------------------------------------------------------------------------
// Dual MFMA GEMM (two independent problems, block-range split), bf16 in/out.
// ---------------------------------------------------------------------------
__global__ __launch_bounds__(256, 2)
void gemm_dual(const bf16* __restrict__ A0, const bf16* __restrict__ W0,
               const bf16* __restrict__ bias0, bf16* __restrict__ out0,
               int N0, int tiles0, int nblk0,
               const bf16* __restrict__ A1, const bf16* __restrict__ W1,
               const bf16* __restrict__ bias1, bf16* __restrict__ out1,
               int N1, int tiles1)
{
    __shared__ __align__(16) bf16 As[4 * QSTRIDE];
    __shared__ __align__(16) bf16 Bs[4 * QSTRIDE];

    const int t    = threadIdx.x;
    const int lane = t & 63;
    const int w    = t >> 6;
    const int wm   = (w >> 1) * 64;
    const int wn   = (w & 1) * 64;

    const bool second = (blockIdx.x >= (unsigned)nblk0);
    const int  bi     = second ? (blockIdx.x - nblk0) : blockIdx.x;
    const bf16* __restrict__ A    = second ? A1 : A0;
    const bf16* __restrict__ W    = second ? W1 : W0;
    const bf16* __restrict__ bias = second ? bias1 : bias0;
    bf16* __restrict__ outB       = second ? out1 : out0;
    const int N      = second ? N1 : N0;
    const int tilesN = second ? tiles1 : tiles0;
    const int tm = (bi / tilesN) * 128;
    const int tn = (bi % tilesN) * 128;

    f32x4 acc[4][4];
#pragma unroll
    for (int i = 0; i < 4; i++)
#pragma unroll
        for (int j = 0; j < 4; j++)
#pragma unroll
            for (int r = 0; r < 4; r++) acc[i][j][r] = 0.f;

    const int m0 = t >> 2,         q0 = t & 3;
    const int m1 = (t + 256) >> 2, q1 = (t + 256) & 3;
    const int fq = lane >> 4, fr = lane & 15;

    for (int k0 = 0; k0 < 256; k0 += 32) {
        s16x8 sa0 = *(const s16x8*)(A + (size_t)(tm + m0) * 256 + k0 + q0 * 8);
        s16x8 sa1 = *(const s16x8*)(A + (size_t)(tm + m1) * 256 + k0 + q1 * 8);
        s16x8 sb0 = *(const s16x8*)(W + (size_t)(tn + m0) * 256 + k0 + q0 * 8);
        s16x8 sb1 = *(const s16x8*)(W + (size_t)(tn + m1) * 256 + k0 + q1 * 8);

        __syncthreads();
        *(s16x8*)&As[q0 * QSTRIDE + m0 * 8] = sa0;
        *(s16x8*)&As[q1 * QSTRIDE + m1 * 8] = sa1;
        *(s16x8*)&Bs[q0 * QSTRIDE + m0 * 8] = sb0;
        *(s16x8*)&Bs[q1 * QSTRIDE + m1 * 8] = sb1;
        __syncthreads();

        s16x8 af[4], bfv[4];
#pragma unroll
        for (int i = 0; i < 4; i++) {
            af[i]  = *(const s16x8*)&As[fq * QSTRIDE + (wm + i * 16 + fr) * 8];
            bfv[i] = *(const s16x8*)&Bs[fq * QSTRIDE + (wn + i * 16 + fr) * 8];
        }
#pragma unroll
        for (int i = 0; i < 4; i++)
#pragma unroll
            for (int j = 0; j < 4; j++)
                acc[i][j] = __builtin_amdgcn_mfma_f32_16x16x32_bf16(
                    af[i], bfv[j], acc[i][j], 0, 0, 0);
    }

#pragma unroll
    for (int j = 0; j < 4; j++) {
        const int ncol = tn + wn + j * 16 + fr;
        const float bj = __bfloat162float(bias[ncol]);
#pragma unroll
        for (int i = 0; i < 4; i++)
#pragma unroll
            for (int r = 0; r < 4; r++) {
                const int mrow = tm + wm + i * 16 + fq * 4 + r;
                outB[(size_t)mrow * N + ncol] = __float2bfloat16(acc[i][j][r] + bj);
            }
    }
}

// ---------------------------------------------------------------------------
// Fused out-proj + residual + LayerNorm. Block = 64 rows x 256 cols.
// y = LN(xp + A@W^T + bias) * g + b -> fp32 d_out (+ optional bf16 copy).
// ---------------------------------------------------------------------------
__global__ __launch_bounds__(256, 2)
void gemm_ln(const bf16* __restrict__ A, const bf16* __restrict__ W,
             const float* __restrict__ biasF, const bf16* __restrict__ xp,
             const float* __restrict__ g, const float* __restrict__ b,
             float* __restrict__ outF, bf16* __restrict__ outB)
{
    __shared__ __align__(16) bf16 As[4 * ASTRIDE];
    __shared__ __align__(16) bf16 Bs[4 * BSTRIDE];
    __shared__ float rs1[64], rs2[64];

    const int t    = threadIdx.x;
    const int lane = t & 63;
    const int w    = t >> 6;
    const int fq   = lane >> 4;
    const int fr   = lane & 15;
    const int tm   = blockIdx.x * 64;

    if (t < 64) { rs1[t] = 0.f; rs2[t] = 0.f; }

    f32x4 acc[4][4];
#pragma unroll
    for (int i = 0; i < 4; i++)
#pragma unroll
        for (int j = 0; j < 4; j++)
#pragma unroll
            for (int r = 0; r < 4; r++) acc[i][j][r] = 0.f;

    const int mA = t >> 2, qA = t & 3;

    for (int k0 = 0; k0 < 256; k0 += 32) {
        s16x8 sa = *(const s16x8*)(A + (size_t)(tm + mA) * 256 + k0 + qA * 8);
        s16x8 sb[4];
#pragma unroll
        for (int s = 0; s < 4; s++)
            sb[s] = *(const s16x8*)(W + (size_t)(mA + 64 * s) * 256 + k0 + qA * 8);

        __syncthreads();
        *(s16x8*)&As[qA * ASTRIDE + mA * 8] = sa;
#pragma unroll
        for (int s = 0; s < 4; s++)
            *(s16x8*)&Bs[qA * BSTRIDE + (mA + 64 * s) * 8] = sb[s];
        __syncthreads();

        s16x8 af[4], bfv[4];
#pragma unroll
        for (int i = 0; i < 4; i++) {
            af[i]  = *(const s16x8*)&As[fq * ASTRIDE + (i * 16 + fr) * 8];
            bfv[i] = *(const s16x8*)&Bs[fq * BSTRIDE + (w * 64 + i * 16 + fr) * 8];
        }
#pragma unroll
        for (int i = 0; i < 4; i++)
#pragma unroll
            for (int j = 0; j < 4; j++)
                acc[i][j] = __builtin_amdgcn_mfma_f32_16x16x32_bf16(
                    af[i], bfv[j], acc[i][j], 0, 0, 0);
    }

    float bj[4], gj[4], bbj[4];
    int colv[4];
#pragma unroll
    for (int j = 0; j < 4; j++) {
        colv[j] = w * 64 + j * 16 + fr;
        bj[j]  = biasF[colv[j]];
        gj[j]  = g[colv[j]];
        bbj[j] = b[colv[j]];
    }

#pragma unroll
    for (int i = 0; i < 4; i++) {
#pragma unroll
        for (int r = 0; r < 4; r++) {
            const int row = i * 16 + fq * 4 + r;
            float t1 = 0.f, t2 = 0.f;
#pragma unroll
            for (int j = 0; j < 4; j++) {
                float v = acc[i][j][r] + bj[j]
                        + __bfloat162float(xp[(size_t)(tm + row) * 256 + colv[j]]);
                acc[i][j][r] = v;
                t1 += v;
                t2 += v * v;
            }
#pragma unroll
            for (int o = 1; o < 16; o <<= 1) {
                t1 += __shfl_xor(t1, o);
                t2 += __shfl_xor(t2, o);
            }
            if (fr == 0) {
                atomicAdd(&rs1[row], t1);
                atomicAdd(&rs2[row], t2);
            }
        }
    }
    __syncthreads();

#pragma unroll
    for (int i = 0; i < 4; i++) {
#pragma unroll
        for (int r = 0; r < 4; r++) {
            const int row = i * 16 + fq * 4 + r;
            const float mu  = rs1[row] * (1.f / 256.f);
            const float var = rs2[row] * (1.f / 256.f) - mu * mu;
            const float rstd = rsqrtf(var + 1e-5f);
#pragma unroll
            for (int j = 0; j < 4; j++) {
                const float y = (acc[i][j][r] - mu) * rstd * gj[j] + bbj[j];
                outF[(size_t)(tm + row) * 256 + colv[j]] = y;
                if (outB) outB[(size_t)(tm + row) * 256 + colv[j]] = __float2bfloat16(y);
            }
        }
    }
}

// ---------------------------------------------------------------------------
// Sparse masked attention, vectorized gather. Block = query row, wave = head.
// 8 groups x 8 lanes: group = neighbor, lane = 8-dim slice (16 B loads).
// ---------------------------------------------------------------------------
__global__ __launch_bounds__(256)
void sparse_attn(const bf16* __restrict__ Q, int qs,
                 const bf16* __restrict__ Kb, const bf16* __restrict__ Vb, int kvs,
                 const int* __restrict__ cnts, const unsigned short* __restrict__ idx,
                 int lmax, int idxmask, bf16* __restrict__ out)
{
    __shared__ float sc[4][CMAX];
    __shared__ unsigned short nls[CMAX];
    const int qi   = blockIdx.x;
    const int h    = threadIdx.x >> 6;
    const int lane = threadIdx.x & 63;
    const int grp  = lane >> 3;
    const int sub  = lane & 7;

    int n = cnts[qi];
    if (n > lmax) n = lmax;

    if (h == 0)
        for (int i = lane; i < n; i += 64)
            nls[i] = (unsigned short)(((int)idx[(size_t)qi * lmax + i]) & idxmask);
    __syncthreads();

    if (n <= 0) {
        out[(size_t)qi * 256 + h * 64 + lane] = __float2bfloat16(0.f);
        return;
    }

    float qv[8];
    {
        union { f32x4 v; unsigned short u[8]; } qu;
        qu.v = *(const f32x4*)(Q + (size_t)qi * qs + h * 64 + sub * 8);
#pragma unroll
        for (int j = 0; j < 8; j++)
            qv[j] = __uint_as_float(((unsigned)qu.u[j]) << 16) * 0.125f;
    }

    float mx = -1e30f;
#pragma unroll 2
    for (int base = 0; base < n; base += 8) {
        const int i = base + grp;
        float s = -1e30f;
        if (i < n) {
            const int nb = nls[i];
            union { f32x4 v; unsigned short u[8]; } ku;
            ku.v = *(const f32x4*)(Kb + (size_t)nb * kvs + h * 64 + sub * 8);
            float a = 0.f;
#pragma unroll
            for (int j = 0; j < 8; j++)
                a += __uint_as_float(((unsigned)ku.u[j]) << 16) * qv[j];
            a += __shfl_xor(a, 1);
            a += __shfl_xor(a, 2);
            a += __shfl_xor(a, 4);
            if (sub == 0) sc[h][i] = a;
            s = a;
        }
        mx = fmaxf(mx, s);
    }
#pragma unroll
    for (int o = 32; o > 0; o >>= 1) mx = fmaxf(mx, __shfl_xor(mx, o));

    float sum = 0.f;
    for (int base = 0; base < n; base += 64) {
        const int i = base + lane;
        if (i < n) {
            const float p = __expf(sc[h][i] - mx);
            sc[h][i] = p;
            sum += p;
        }
    }
#pragma unroll
    for (int o = 32; o > 0; o >>= 1) sum += __shfl_xor(sum, o);
    const float inv = 1.f / sum;

    float oa[8];
#pragma unroll
    for (int j = 0; j < 8; j++) oa[j] = 0.f;
#pragma unroll 2
    for (int base = 0; base < n; base += 8) {
        const int i = base + grp;
        if (i < n) {
            const float p = sc[h][i];
            const int nb = nls[i];
            union { f32x4 v; unsigned short u[8]; } vu;
            vu.v = *(const f32x4*)(Vb + (size_t)nb * kvs + h * 64 + sub * 8);
#pragma unroll
            for (int j = 0; j < 8; j++)
                oa[j] += p * __uint_as_float(((unsigned)vu.u[j]) << 16);
        }
    }
#pragma unroll
    for (int j = 0; j < 8; j++) {
        oa[j] += __shfl_xor(oa[j], 8);
        oa[j] += __shfl_xor(oa[j], 16);
        oa[j] += __shfl_xor(oa[j], 32);
    }
    if (grp == 0) {
        union { s16x8 v; bf16 e[8]; } ou;
#pragma unroll
        for (int j = 0; j < 8; j++) ou.e[j] = __float2bfloat16(oa[j] * inv);
        *(s16x8*)(out + (size_t)qi * 256 + h * 64 + sub * 8) = ou.v;
    }
}

// ---------------------------------------------------------------------------
extern "C" void kernel_launch(void* const* d_in, const int* in_sizes, int n_in,
                              void* d_out, int out_size, void* d_ws, size_t ws_size,
                              hipStream_t stream)
{
    const int N = 8192, E = 2048;

    float* out0 = (float*)d_out;                   // x_0_u [N,256] fp32
    float* out1 = (float*)d_out + (size_t)N * 256; // x_1_u [E,256] fp32

    char* wp = (char*)d_ws;
    auto carve = [&](size_t bytes) { void* p = wp; wp += (bytes + 15) & ~size_t(15); return p; };

    bf16*  wcat    = (bf16*)          carve(657408 * 2);
    int*   col_cnt = (int*)           carve((size_t)E * 4);
    int*   row_cnt = (int*)           carve((size_t)N * 4);
    unsigned short* col_idx = (unsigned short*)carve((size_t)E * CMAX * 2);
    unsigned short* row_idx = (unsigned short*)carve((size_t)N * RMAX * 2);
    bf16*  xp01    = (bf16*) carve((size_t)(N + E) * 256 * 2);  // x0p | x1p
    bf16*  kvq     = (bf16*) carve((size_t)N * 768 * 2);        // k1|v1|q2
    bf16*  q1      = (bf16*) carve((size_t)E * 256 * 2);
    bf16*  attn1   = (bf16*) carve((size_t)E * 256 * 2);
    bf16*  x1u_b   = (bf16*) carve((size_t)E * 256 * 2);
    bf16*  kv2     = (bf16*) carve((size_t)E * 512 * 2);
    bf16*  attn2   = (bf16*) carve((size_t)N * 256 * 2);

    bf16* x0p = xp01;
    bf16* x1p = xp01 + (size_t)N * 256;

    // wcat element offsets (all 8-elem aligned)
    const int O_PW   = 0;        // node_w | edge_w           (131072)
    const int O_PB   = 131072;   // node_b | edge_b           (512)
    const int O_KVQ  = 131584;   // n2e Wk,Wv | e2n Wq        (196608)
    const int O_KVQB = 328192;   // n2e bk,bv | e2n bq        (768)
    const int O_Q1W  = 328960;   // n2e Wq                    (65536)
    const int O_Q1B  = 394496;   // n2e bq                    (256)
    const int O_KV2W = 394752;   // e2n Wk,Wv                 (131072)
    const int O_KV2B = 525824;   // e2n bk,bv                 (512)
    const int O_O1W  = 526336;   // n2e_out_w                 (65536)
    const int O_O2W  = 591872;   // e2n_out_w                 (65536)

    ConvDesc cd;
    const float* srcs[14] = {
        (const float*)d_in[3], (const float*)d_in[5],
        (const float*)d_in[4], (const float*)d_in[6],
        (const float*)d_in[7] + 65536, (const float*)d_in[11],
        (const float*)d_in[8] + 256,   (const float*)d_in[12],
        (const float*)d_in[7],         (const float*)d_in[8],
        (const float*)d_in[11] + 65536,(const float*)d_in[12] + 256,
        (const float*)d_in[9],         (const float*)d_in[13]
    };
    const int offs[14] = {O_PW, O_PW + 65536, O_PB, O_PB + 256,
                          O_KVQ, O_KVQ + 131072, O_KVQB, O_KVQB + 512,
                          O_Q1W, O_Q1B, O_KV2W, O_KV2B, O_O1W, O_O2W};
    const int cnts[14] = {65536, 65536, 256, 256, 131072, 65536, 512, 256,
                          65536, 256, 131072, 512, 65536, 65536};
    for (int i = 0; i < 14; i++) { cd.src[i] = srcs[i]; cd.dstoff[i] = offs[i]; cd.cnt[i] = cnts[i]; }

    // 1. weights -> bf16 arena + zero col_cnt (seg 14)
    conv_weights<<<15 * 64, 256, 0, stream>>>(cd, wcat, col_cnt, E);

    // 2. sparse lists (r11 known-best: streaming + prefetch + inline atomics)
    build_lists<<<1024, 256, 0, stream>>>((const float*)d_in[2], col_cnt, col_idx,
                                          row_cnt, row_idx);

    // 3. projections
    gemm_proj<<<160, 256, 0, stream>>>((const float*)d_in[0], (const float*)d_in[1],
                                       wcat + O_PW, wcat + O_PB, xp01);

    // 4. fused kvq (384 blocks) + q1 (32 blocks)
    gemm_dual<<<384 + 32, 256, 0, stream>>>(x0p, wcat + O_KVQ, wcat + O_KVQB, kvq,
                                            768, 6, 384,
                                            x1p, wcat + O_Q1W, wcat + O_Q1B, q1,
                                            256, 2);

    // ---- stage 1: node -> edge ----
    sparse_attn<<<E, 256, 0, stream>>>(q1, 256, kvq, kvq + 256, 768,
                                       col_cnt, col_idx, CMAX, N - 1, attn1);
    gemm_ln<<<E / 64, 256, 0, stream>>>(attn1, wcat + O_O1W, (const float*)d_in[10],
                                        x1p, (const float*)d_in[15], (const float*)d_in[16],
                                        out1, x1u_b);

    // ---- stage 2: edge -> node ----
    gemm_dual<<<64, 256, 0, stream>>>(x1u_b, wcat + O_KV2W, wcat + O_KV2B, kv2,
                                      512, 4, 64,
                                      nullptr, nullptr, nullptr, nullptr, 256, 2);
    sparse_attn<<<N, 256, 0, stream>>>(kvq + 512, 768, kv2, kv2 + 256, 512,
                                       row_cnt, row_idx, RMAX, E - 1, attn2);
    gemm_ln<<<N / 64, 256, 0, stream>>>(attn2, wcat + O_O2W, (const float*)d_in[14],
                                        x0p, (const float*)d_in[17], (const float*)d_in[18],
                                        out0, nullptr);
}

// Round 16
// 269.118 us; speedup vs baseline: 3.8412x; 1.0099x over previous
//
#include <hip/hip_runtime.h>
#include <hip/hip_bf16.h>

using bf16 = __hip_bfloat16;
typedef __attribute__((ext_vector_type(4))) float  f32x4;
typedef __attribute__((ext_vector_type(8))) short  s16x8;

#define QSTRIDE 1040   // 128*8 + 16 pad (bf16 elems per k-quad block)
#define ASTRIDE 520    // 64*8 + 8 pad   (gemm_ln A tile)
#define BSTRIDE 2064   // 256*8 + 16 pad (gemm_ln B tile)
#define CMAX 256
#define RMAX 128

// ---------------------------------------------------------------------------
// Merged: weight conversion (segments 0..13, blocks 0..895) + sparse-list
// build (blocks 896..1919). Both paths are featherweight (<=24 VGPR, 4B LDS)
// so co-scheduling does NOT throttle the H-scan (unlike r10's GEMM fusion).
// Build body = r11 known-best (41us): 1024 virtual blocks x 8 rows,
// 2-deep register prefetch, inline atomics. r12/r13/r14 alternatives all
// measured worse (82/70/788 us) — do not revisit.
// col_cnt must be zeroed BEFORE this kernel (tiny memsetAsync) — the
// build blocks' atomics race any in-kernel zeroing.
// ---------------------------------------------------------------------------
struct ConvDesc { const float* src[14]; int dstoff[14]; int cnt[14]; };

__global__ __launch_bounds__(256)
void conv_build(ConvDesc d, bf16* __restrict__ dst,
                const float* __restrict__ H, int* __restrict__ col_cnt,
                unsigned short* __restrict__ col_idx, int* __restrict__ row_cnt,
                unsigned short* __restrict__ row_idx)
{
    __shared__ int rc;
    const int t = threadIdx.x;

    if (blockIdx.x < 14 * 64) {
        // ---- weight conversion path ----
        const int seg = blockIdx.x >> 6;
        const int blk = blockIdx.x & 63;
        const float* __restrict__ s = d.src[seg];
        bf16* __restrict__ o = dst + d.dstoff[seg];
        const int n = d.cnt[seg];
        for (int i = blk * 256 + t; i < n; i += 64 * 256)
            o[i] = __float2bfloat16(s[i]);
        return;
    }

    // ---- build_lists path (r11 body) ----
    int n = blockIdx.x - 14 * 64;            // 0..1023
    const float* Hp = H + (size_t)n * 2048 + t * 8;
    f32x4 c0 = *(const f32x4*)Hp;
    f32x4 c1 = *(const f32x4*)(Hp + 4);

    while (n < 8192) {
        const int nn = n + 1024;
        f32x4 p0, p1;
        if (nn < 8192) {                     // prefetch next row
            const float* Hq = H + (size_t)nn * 2048 + t * 8;
            p0 = *(const f32x4*)Hq;
            p1 = *(const f32x4*)(Hq + 4);
        }

        if (t == 0) rc = 0;
        __syncthreads();

        float hv[8];
#pragma unroll
        for (int j = 0; j < 4; j++) { hv[j] = c0[j]; hv[4 + j] = c1[j]; }

#pragma unroll
        for (int j = 0; j < 8; j++) {
            if (hv[j] != 0.f) {
                const int e = t * 8 + j;
                const int sr = atomicAdd(&rc, 1);
                if (sr < RMAX) row_idx[(size_t)n * RMAX + sr] = (unsigned short)e;
                const int sc = atomicAdd(&col_cnt[e], 1);
                if (sc < CMAX) col_idx[(size_t)e * CMAX + sc] = (unsigned short)n;
            }
        }
        __syncthreads();
        if (t == 0) row_cnt[n] = (rc < RMAX) ? rc : RMAX;

        n = nn; c0 = p0; c1 = p1;
    }
}

// ---------------------------------------------------------------------------
// Fused node+edge projection: rows 0..8191 = x_0@node_w^T+node_b,
// rows 8192..10239 = x_1@edge_w^T+edge_b. A fp32 converted in staging.
// Grid: 80 row-tiles x 2 col-tiles = 160 blocks.
// ---------------------------------------------------------------------------
__global__ __launch_bounds__(256, 2)
void gemm_proj(const float* __restrict__ X0, const float* __restrict__ X1,
               const bf16* __restrict__ Wc, const bf16* __restrict__ biasc,
               bf16* __restrict__ outB)
{
    __shared__ __align__(16) bf16 As[4 * QSTRIDE];
    __shared__ __align__(16) bf16 Bs[4 * QSTRIDE];

    const int t    = threadIdx.x;
    const int lane = t & 63;
    const int w    = t >> 6;
    const int wm   = (w >> 1) * 64;
    const int wn   = (w & 1) * 64;
    const int bt   = blockIdx.x >> 1;
    const int tn   = (blockIdx.x & 1) * 128;
    if (bt >= 80) return;

    const float* __restrict__ A = (bt < 64) ? X0 : X1;
    const int arow = (bt < 64) ? bt * 128 : (bt - 64) * 128;
    const bf16* __restrict__ W    = Wc    + ((bt < 64) ? 0 : 65536);
    const bf16* __restrict__ bias = biasc + ((bt < 64) ? 0 : 256);
    const int tm = bt * 128;

    f32x4 acc[4][4];
#pragma unroll
    for (int i = 0; i < 4; i++)
#pragma unroll
        for (int j = 0; j < 4; j++)
#pragma unroll
            for (int r = 0; r < 4; r++) acc[i][j][r] = 0.f;

    const int m0 = t >> 2,         q0 = t & 3;
    const int m1 = (t + 256) >> 2, q1 = (t + 256) & 3;
    const int fq = lane >> 4, fr = lane & 15;

    for (int k0 = 0; k0 < 256; k0 += 32) {
        f32x4 a0l = *(const f32x4*)(A + (size_t)(arow + m0) * 256 + k0 + q0 * 8);
        f32x4 a0h = *(const f32x4*)(A + (size_t)(arow + m0) * 256 + k0 + q0 * 8 + 4);
        f32x4 a1l = *(const f32x4*)(A + (size_t)(arow + m1) * 256 + k0 + q1 * 8);
        f32x4 a1h = *(const f32x4*)(A + (size_t)(arow + m1) * 256 + k0 + q1 * 8 + 4);
        union { s16x8 v; bf16 e[8]; } u0, u1;
#pragma unroll
        for (int j = 0; j < 4; j++) {
            u0.e[j] = __float2bfloat16(a0l[j]); u0.e[4 + j] = __float2bfloat16(a0h[j]);
            u1.e[j] = __float2bfloat16(a1l[j]); u1.e[4 + j] = __float2bfloat16(a1h[j]);
        }
        s16x8 sb0 = *(const s16x8*)(W + (size_t)(tn + m0) * 256 + k0 + q0 * 8);
        s16x8 sb1 = *(const s16x8*)(W + (size_t)(tn + m1) * 256 + k0 + q1 * 8);

        __syncthreads();
        *(s16x8*)&As[q0 * QSTRIDE + m0 * 8] = u0.v;
        *(s16x8*)&As[q1 * QSTRIDE + m1 * 8] = u1.v;
        *(s16x8*)&Bs[q0 * QSTRIDE + m0 * 8] = sb0;
        *(s16x8*)&Bs[q1 * QSTRIDE + m1 * 8] = sb1;
        __syncthreads();

        s16x8 af[4], bfv[4];
#pragma unroll
        for (int i = 0; i < 4; i++) {
            af[i]  = *(const s16x8*)&As[fq * QSTRIDE + (wm + i * 16 + fr) * 8];
            bfv[i] = *(const s16x8*)&Bs[fq * QSTRIDE + (wn + i * 16 + fr) * 8];
        }
#pragma unroll
        for (int i = 0; i < 4; i++)
#pragma unroll
            for (int j = 0; j < 4; j++)
                acc[i][j] = __builtin_amdgcn_mfma_f32_16x16x32_bf16(
                    af[i], bfv[j], acc[i][j], 0, 0, 0);
    }

#pragma unroll
    for (int j = 0; j < 4; j++) {
        const int ncol = tn + wn + j * 16 + fr;
        const float bj = __bfloat162float(bias[ncol]);
#pragma unroll
        for (int i = 0; i < 4; i++)
#pragma unroll
            for (int r = 0; r < 4; r++) {
                const int mrow = tm + wm + i * 16 + fq * 4 + r;
                outB[(size_t)mrow * 256 + ncol] = __float2bfloat16(acc[i][j][r] + bj);
            }
    }
}

// ---------------------------------------------------------------------------
// Dual MFMA GEMM (two independent problems, block-range split), bf16 in/out.
// ---------------------------------------------------------------------------
__global__ __launch_bounds__(256, 2)
void gemm_dual(const bf16* __restrict__ A0, const bf16* __restrict__ W0,
               const bf16* __restrict__ bias0, bf16* __restrict__ out0,
               int N0, int tiles0, int nblk0,
               const bf16* __restrict__ A1, const bf16* __restrict__ W1,
               const bf16* __restrict__ bias1, bf16* __restrict__ out1,
               int N1, int tiles1)
{
    __shared__ __align__(16) bf16 As[4 * QSTRIDE];
    __shared__ __align__(16) bf16 Bs[4 * QSTRIDE];

    const int t    = threadIdx.x;
    const int lane = t & 63;
    const int w    = t >> 6;
    const int wm   = (w >> 1) * 64;
    const int wn   = (w & 1) * 64;

    const bool second = (blockIdx.x >= (unsigned)nblk0);
    const int  bi     = second ? (blockIdx.x - nblk0) : blockIdx.x;
    const bf16* __restrict__ A    = second ? A1 : A0;
    const bf16* __restrict__ W    = second ? W1 : W0;
    const bf16* __restrict__ bias = second ? bias1 : bias0;
    bf16* __restrict__ outB       = second ? out1 : out0;
    const int N      = second ? N1 : N0;
    const int tilesN = second ? tiles1 : tiles0;
    const int tm = (bi / tilesN) * 128;
    const int tn = (bi % tilesN) * 128;

    f32x4 acc[4][4];
#pragma unroll
    for (int i = 0; i < 4; i++)
#pragma unroll
        for (int j = 0; j < 4; j++)
#pragma unroll
            for (int r = 0; r < 4; r++) acc[i][j][r] = 0.f;

    const int m0 = t >> 2,         q0 = t & 3;
    const int m1 = (t + 256) >> 2, q1 = (t + 256) & 3;
    const int fq = lane >> 4, fr = lane & 15;

    for (int k0 = 0; k0 < 256; k0 += 32) {
        s16x8 sa0 = *(const s16x8*)(A + (size_t)(tm + m0) * 256 + k0 + q0 * 8);
        s16x8 sa1 = *(const s16x8*)(A + (size_t)(tm + m1) * 256 + k0 + q1 * 8);
        s16x8 sb0 = *(const s16x8*)(W + (size_t)(tn + m0) * 256 + k0 + q0 * 8);
        s16x8 sb1 = *(const s16x8*)(W + (size_t)(tn + m1) * 256 + k0 + q1 * 8);

        __syncthreads();
        *(s16x8*)&As[q0 * QSTRIDE + m0 * 8] = sa0;
        *(s16x8*)&As[q1 * QSTRIDE + m1 * 8] = sa1;
        *(s16x8*)&Bs[q0 * QSTRIDE + m0 * 8] = sb0;
        *(s16x8*)&Bs[q1 * QSTRIDE + m1 * 8] = sb1;
        __syncthreads();

        s16x8 af[4], bfv[4];
#pragma unroll
        for (int i = 0; i < 4; i++) {
            af[i]  = *(const s16x8*)&As[fq * QSTRIDE + (wm + i * 16 + fr) * 8];
            bfv[i] = *(const s16x8*)&Bs[fq * QSTRIDE + (wn + i * 16 + fr) * 8];
        }
#pragma unroll
        for (int i = 0; i < 4; i++)
#pragma unroll
            for (int j = 0; j < 4; j++)
                acc[i][j] = __builtin_amdgcn_mfma_f32_16x16x32_bf16(
                    af[i], bfv[j], acc[i][j], 0, 0, 0);
    }

#pragma unroll
    for (int j = 0; j < 4; j++) {
        const int ncol = tn + wn + j * 16 + fr;
        const float bj = __bfloat162float(bias[ncol]);
#pragma unroll
        for (int i = 0; i < 4; i++)
#pragma unroll
            for (int r = 0; r < 4; r++) {
                const int mrow = tm + wm + i * 16 + fq * 4 + r;
                outB[(size_t)mrow * N + ncol] = __float2bfloat16(acc[i][j][r] + bj);
            }
    }
}

// ---------------------------------------------------------------------------
// Fused out-proj + residual + LayerNorm. Block = 64 rows x 256 cols.
// y = LN(xp + A@W^T + bias) * g + b -> fp32 d_out (+ optional bf16 copy).
// ---------------------------------------------------------------------------
__global__ __launch_bounds__(256, 2)
void gemm_ln(const bf16* __restrict__ A, const bf16* __restrict__ W,
             const float* __restrict__ biasF, const bf16* __restrict__ xp,
             const float* __restrict__ g, const float* __restrict__ b,
             float* __restrict__ outF, bf16* __restrict__ outB)
{
    __shared__ __align__(16) bf16 As[4 * ASTRIDE];
    __shared__ __align__(16) bf16 Bs[4 * BSTRIDE];
    __shared__ float rs1[64], rs2[64];

    const int t    = threadIdx.x;
    const int lane = t & 63;
    const int w    = t >> 6;
    const int fq   = lane >> 4;
    const int fr   = lane & 15;
    const int tm   = blockIdx.x * 64;

    if (t < 64) { rs1[t] = 0.f; rs2[t] = 0.f; }

    f32x4 acc[4][4];
#pragma unroll
    for (int i = 0; i < 4; i++)
#pragma unroll
        for (int j = 0; j < 4; j++)
#pragma unroll
            for (int r = 0; r < 4; r++) acc[i][j][r] = 0.f;

    const int mA = t >> 2, qA = t & 3;

    for (int k0 = 0; k0 < 256; k0 += 32) {
        s16x8 sa = *(const s16x8*)(A + (size_t)(tm + mA) * 256 + k0 + qA * 8);
        s16x8 sb[4];
#pragma unroll
        for (int s = 0; s < 4; s++)
            sb[s] = *(const s16x8*)(W + (size_t)(mA + 64 * s) * 256 + k0 + qA * 8);

        __syncthreads();
        *(s16x8*)&As[qA * ASTRIDE + mA * 8] = sa;
#pragma unroll
        for (int s = 0; s < 4; s++)
            *(s16x8*)&Bs[qA * BSTRIDE + (mA + 64 * s) * 8] = sb[s];
        __syncthreads();

        s16x8 af[4], bfv[4];
#pragma unroll
        for (int i = 0; i < 4; i++) {
            af[i]  = *(const s16x8*)&As[fq * ASTRIDE + (i * 16 + fr) * 8];
            bfv[i] = *(const s16x8*)&Bs[fq * BSTRIDE + (w * 64 + i * 16 + fr) * 8];
        }
#pragma unroll
        for (int i = 0; i < 4; i++)
#pragma unroll
            for (int j = 0; j < 4; j++)
                acc[i][j] = __builtin_amdgcn_mfma_f32_16x16x32_bf16(
                    af[i], bfv[j], acc[i][j], 0, 0, 0);
    }

    float bj[4], gj[4], bbj[4];
    int colv[4];
#pragma unroll
    for (int j = 0; j < 4; j++) {
        colv[j] = w * 64 + j * 16 + fr;
        bj[j]  = biasF[colv[j]];
        gj[j]  = g[colv[j]];
        bbj[j] = b[colv[j]];
    }

#pragma unroll
    for (int i = 0; i < 4; i++) {
#pragma unroll
        for (int r = 0; r < 4; r++) {
            const int row = i * 16 + fq * 4 + r;
            float t1 = 0.f, t2 = 0.f;
#pragma unroll
            for (int j = 0; j < 4; j++) {
                float v = acc[i][j][r] + bj[j]
                        + __bfloat162float(xp[(size_t)(tm + row) * 256 + colv[j]]);
                acc[i][j][r] = v;
                t1 += v;
                t2 += v * v;
            }
#pragma unroll
            for (int o = 1; o < 16; o <<= 1) {
                t1 += __shfl_xor(t1, o);
                t2 += __shfl_xor(t2, o);
            }
            if (fr == 0) {
                atomicAdd(&rs1[row], t1);
                atomicAdd(&rs2[row], t2);
            }
        }
    }
    __syncthreads();

#pragma unroll
    for (int i = 0; i < 4; i++) {
#pragma unroll
        for (int r = 0; r < 4; r++) {
            const int row = i * 16 + fq * 4 + r;
            const float mu  = rs1[row] * (1.f / 256.f);
            const float var = rs2[row] * (1.f / 256.f) - mu * mu;
            const float rstd = rsqrtf(var + 1e-5f);
#pragma unroll
            for (int j = 0; j < 4; j++) {
                const float y = (acc[i][j][r] - mu) * rstd * gj[j] + bbj[j];
                outF[(size_t)(tm + row) * 256 + colv[j]] = y;
                if (outB) outB[(size_t)(tm + row) * 256 + colv[j]] = __float2bfloat16(y);
            }
        }
    }
}

// ---------------------------------------------------------------------------
// Sparse masked attention, vectorized gather. Block = query row, wave = head.
// 8 groups x 8 lanes: group = neighbor, lane = 8-dim slice (16 B loads).
// ---------------------------------------------------------------------------
__global__ __launch_bounds__(256)
void sparse_attn(const bf16* __restrict__ Q, int qs,
                 const bf16* __restrict__ Kb, const bf16* __restrict__ Vb, int kvs,
                 const int* __restrict__ cnts, const unsigned short* __restrict__ idx,
                 int lmax, int idxmask, bf16* __restrict__ out)
{
    __shared__ float sc[4][CMAX];
    __shared__ unsigned short nls[CMAX];
    const int qi   = blockIdx.x;
    const int h    = threadIdx.x >> 6;
    const int lane = threadIdx.x & 63;
    const int grp  = lane >> 3;
    const int sub  = lane & 7;

    int n = cnts[qi];
    if (n > lmax) n = lmax;

    if (h == 0)
        for (int i = lane; i < n; i += 64)
            nls[i] = (unsigned short)(((int)idx[(size_t)qi * lmax + i]) & idxmask);
    __syncthreads();

    if (n <= 0) {
        out[(size_t)qi * 256 + h * 64 + lane] = __float2bfloat16(0.f);
        return;
    }

    float qv[8];
    {
        union { f32x4 v; unsigned short u[8]; } qu;
        qu.v = *(const f32x4*)(Q + (size_t)qi * qs + h * 64 + sub * 8);
#pragma unroll
        for (int j = 0; j < 8; j++)
            qv[j] = __uint_as_float(((unsigned)qu.u[j]) << 16) * 0.125f;
    }

    float mx = -1e30f;
#pragma unroll 2
    for (int base = 0; base < n; base += 8) {
        const int i = base + grp;
        float s = -1e30f;
        if (i < n) {
            const int nb = nls[i];
            union { f32x4 v; unsigned short u[8]; } ku;
            ku.v = *(const f32x4*)(Kb + (size_t)nb * kvs + h * 64 + sub * 8);
            float a = 0.f;
#pragma unroll
            for (int j = 0; j < 8; j++)
                a += __uint_as_float(((unsigned)ku.u[j]) << 16) * qv[j];
            a += __shfl_xor(a, 1);
            a += __shfl_xor(a, 2);
            a += __shfl_xor(a, 4);
            if (sub == 0) sc[h][i] = a;
            s = a;
        }
        mx = fmaxf(mx, s);
    }
#pragma unroll
    for (int o = 32; o > 0; o >>= 1) mx = fmaxf(mx, __shfl_xor(mx, o));

    float sum = 0.f;
    for (int base = 0; base < n; base += 64) {
        const int i = base + lane;
        if (i < n) {
            const float p = __expf(sc[h][i] - mx);
            sc[h][i] = p;
            sum += p;
        }
    }
#pragma unroll
    for (int o = 32; o > 0; o >>= 1) sum += __shfl_xor(sum, o);
    const float inv = 1.f / sum;

    float oa[8];
#pragma unroll
    for (int j = 0; j < 8; j++) oa[j] = 0.f;
#pragma unroll 2
    for (int base = 0; base < n; base += 8) {
        const int i = base + grp;
        if (i < n) {
            const float p = sc[h][i];
            const int nb = nls[i];
            union { f32x4 v; unsigned short u[8]; } vu;
            vu.v = *(const f32x4*)(Vb + (size_t)nb * kvs + h * 64 + sub * 8);
#pragma unroll
            for (int j = 0; j < 8; j++)
                oa[j] += p * __uint_as_float(((unsigned)vu.u[j]) << 16);
        }
    }
#pragma unroll
    for (int j = 0; j < 8; j++) {
        oa[j] += __shfl_xor(oa[j], 8);
        oa[j] += __shfl_xor(oa[j], 16);
        oa[j] += __shfl_xor(oa[j], 32);
    }
    if (grp == 0) {
        union { s16x8 v; bf16 e[8]; } ou;
#pragma unroll
        for (int j = 0; j < 8; j++) ou.e[j] = __float2bfloat16(oa[j] * inv);
        *(s16x8*)(out + (size_t)qi * 256 + h * 64 + sub * 8) = ou.v;
    }
}

// ---------------------------------------------------------------------------
extern "C" void kernel_launch(void* const* d_in, const int* in_sizes, int n_in,
                              void* d_out, int out_size, void* d_ws, size_t ws_size,
                              hipStream_t stream)
{
    const int N = 8192, E = 2048;

    float* out0 = (float*)d_out;                   // x_0_u [N,256] fp32
    float* out1 = (float*)d_out + (size_t)N * 256; // x_1_u [E,256] fp32

    char* wp = (char*)d_ws;
    auto carve = [&](size_t bytes) { void* p = wp; wp += (bytes + 15) & ~size_t(15); return p; };

    bf16*  wcat    = (bf16*)          carve(657408 * 2);
    int*   col_cnt = (int*)           carve((size_t)E * 4);
    int*   row_cnt = (int*)           carve((size_t)N * 4);
    unsigned short* col_idx = (unsigned short*)carve((size_t)E * CMAX * 2);
    unsigned short* row_idx = (unsigned short*)carve((size_t)N * RMAX * 2);
    bf16*  xp01    = (bf16*) carve((size_t)(N + E) * 256 * 2);  // x0p | x1p
    bf16*  kvq     = (bf16*) carve((size_t)N * 768 * 2);        // k1|v1|q2
    bf16*  q1      = (bf16*) carve((size_t)E * 256 * 2);
    bf16*  attn1   = (bf16*) carve((size_t)E * 256 * 2);
    bf16*  x1u_b   = (bf16*) carve((size_t)E * 256 * 2);
    bf16*  kv2     = (bf16*) carve((size_t)E * 512 * 2);
    bf16*  attn2   = (bf16*) carve((size_t)N * 256 * 2);

    bf16* x0p = xp01;
    bf16* x1p = xp01 + (size_t)N * 256;

    // wcat element offsets (all 8-elem aligned)
    const int O_PW   = 0;        // node_w | edge_w           (131072)
    const int O_PB   = 131072;   // node_b | edge_b           (512)
    const int O_KVQ  = 131584;   // n2e Wk,Wv | e2n Wq        (196608)
    const int O_KVQB = 328192;   // n2e bk,bv | e2n bq        (768)
    const int O_Q1W  = 328960;   // n2e Wq                    (65536)
    const int O_Q1B  = 394496;   // n2e bq                    (256)
    const int O_KV2W = 394752;   // e2n Wk,Wv                 (131072)
    const int O_KV2B = 525824;   // e2n bk,bv                 (512)
    const int O_O1W  = 526336;   // n2e_out_w                 (65536)
    const int O_O2W  = 591872;   // e2n_out_w                 (65536)

    ConvDesc cd;
    const float* srcs[14] = {
        (const float*)d_in[3], (const float*)d_in[5],
        (const float*)d_in[4], (const float*)d_in[6],
        (const float*)d_in[7] + 65536, (const float*)d_in[11],
        (const float*)d_in[8] + 256,   (const float*)d_in[12],
        (const float*)d_in[7],         (const float*)d_in[8],
        (const float*)d_in[11] + 65536,(const float*)d_in[12] + 256,
        (const float*)d_in[9],         (const float*)d_in[13]
    };
    const int offs[14] = {O_PW, O_PW + 65536, O_PB, O_PB + 256,
                          O_KVQ, O_KVQ + 131072, O_KVQB, O_KVQB + 512,
                          O_Q1W, O_Q1B, O_KV2W, O_KV2B, O_O1W, O_O2W};
    const int cnts[14] = {65536, 65536, 256, 256, 131072, 65536, 512, 256,
                          65536, 256, 131072, 512, 65536, 65536};
    for (int i = 0; i < 14; i++) { cd.src[i] = srcs[i]; cd.dstoff[i] = offs[i]; cd.cnt[i] = cnts[i]; }

    // 1. zero col_cnt (8 KB, must precede conv_build's atomics)
    hipMemsetAsync(col_cnt, 0, (size_t)E * 4, stream);

    // 2. merged weight-conversion + sparse-list build
    conv_build<<<14 * 64 + 1024, 256, 0, stream>>>(cd, wcat, (const float*)d_in[2],
                                                   col_cnt, col_idx, row_cnt, row_idx);

    // 3. projections
    gemm_proj<<<160, 256, 0, stream>>>((const float*)d_in[0], (const float*)d_in[1],
                                       wcat + O_PW, wcat + O_PB, xp01);

    // 4. fused kvq (384 blocks) + q1 (32 blocks)
    gemm_dual<<<384 + 32, 256, 0, stream>>>(x0p, wcat + O_KVQ, wcat + O_KVQB, kvq,
                                            768, 6, 384,
                                            x1p, wcat + O_Q1W, wcat + O_Q1B, q1,
                                            256, 2);

    // ---- stage 1: node -> edge ----
    sparse_attn<<<E, 256, 0, stream>>>(q1, 256, kvq, kvq + 256, 768,
                                       col_cnt, col_idx, CMAX, N - 1, attn1);
    gemm_ln<<<E / 64, 256, 0, stream>>>(attn1, wcat + O_O1W, (const float*)d_in[10],
                                        x1p, (const float*)d_in[15], (const float*)d_in[16],
                                        out1, x1u_b);

    // ---- stage 2: edge -> node ----
    gemm_dual<<<64, 256, 0, stream>>>(x1u_b, wcat + O_KV2W, wcat + O_KV2B, kv2,
                                      512, 4, 64,
                                      nullptr, nullptr, nullptr, nullptr, 256, 2);
    sparse_attn<<<N, 256, 0, stream>>>(kvq + 512, 768, kv2, kv2 + 256, 512,
                                       row_cnt, row_idx, RMAX, E - 1, attn2);
    gemm_ln<<<N / 64, 256, 0, stream>>>(attn2, wcat + O_O2W, (const float*)d_in[14],
                                        x0p, (const float*)d_in[17], (const float*)d_in[18],
                                        out0, nullptr);
}